// Round 1
// baseline (755.749 us; speedup 1.0000x reference)
//
#include <hip/hip_runtime.h>

#define NN 50000
#define NM 50000
#define F  128

// ---------------- GEMM: x = X @ W  ([NN,128] @ [128,128], f32 vector ALU) --------
__global__ __launch_bounds__(256) void gemm_k(const float* __restrict__ X,
                                              const float* __restrict__ W,
                                              float* __restrict__ xo) {
    __shared__ float sW[128 * 128];   // 64 KB
    __shared__ float sX[16 * 128];    // 8 KB
    int t = threadIdx.x;

    const float4* W4 = (const float4*)W;
    float4* sW4 = (float4*)sW;
#pragma unroll
    for (int i = 0; i < 16; ++i) sW4[i * 256 + t] = W4[i * 256 + t];

    const float4* X4 = (const float4*)(X + (size_t)blockIdx.x * 16 * 128);
    float4* sX4 = (float4*)sX;
    sX4[t]       = X4[t];
    sX4[t + 256] = X4[t + 256];
    __syncthreads();

    int l = t & 63, w = t >> 6;           // lane, wave (4 waves, 4 rows each)
    float acc[4][2] = {};
#pragma unroll 4
    for (int k = 0; k < 128; ++k) {
        float w0 = sW[k * 128 + l];
        float w1 = sW[k * 128 + 64 + l];
#pragma unroll
        for (int r = 0; r < 4; ++r) {
            float xv = sX[(w * 4 + r) * 128 + k];
            acc[r][0] = fmaf(xv, w0, acc[r][0]);
            acc[r][1] = fmaf(xv, w1, acc[r][1]);
        }
    }
    int row0 = blockIdx.x * 16 + w * 4;
#pragma unroll
    for (int r = 0; r < 4; ++r) {
        xo[(size_t)(row0 + r) * 128 + l]      = acc[r][0];
        xo[(size_t)(row0 + r) * 128 + 64 + l] = acc[r][1];
    }
}

// ---------------- degree counting (both directions in one pass) ------------------
__global__ void count_k(const int* __restrict__ nodes, const int* __restrict__ hedges,
                        int* __restrict__ cnt_v, int* __restrict__ cnt_h, int E) {
    int e = blockIdx.x * 256 + threadIdx.x;
    if (e < E) {
        atomicAdd(&cnt_v[nodes[e]], 1);
        atomicAdd(&cnt_h[hedges[e]], 1);
    }
}

// ---------------- single-block exclusive scan (wave-scan + 16 wave sums) ---------
__device__ void scan_one(const int* __restrict__ cnt, int* __restrict__ off,
                         int* __restrict__ cur, int n, int* sbuf /*17 ints*/) {
    int t = threadIdx.x, lane = t & 63, wid = t >> 6;
    int carry = 0;
    if (t == 0) off[0] = 0;
    for (int base = 0; base < n; base += 1024) {
        int i = base + t;
        int v = (i < n) ? cnt[i] : 0;
        int incl = v;
#pragma unroll
        for (int s = 1; s < 64; s <<= 1) {
            int u = __shfl_up(incl, s, 64);
            if (lane >= s) incl += u;
        }
        if (lane == 63) sbuf[wid] = incl;
        __syncthreads();
        if (t < 16) {
            int wv = sbuf[t];
            int wincl = wv;
#pragma unroll
            for (int s = 1; s < 16; s <<= 1) {
                int u = __shfl_up(wincl, s, 64);
                if (t >= s) wincl += u;
            }
            sbuf[t] = wincl - wv;              // exclusive wave offset
            if (t == 15) sbuf[16] = wincl;     // chunk total
        }
        __syncthreads();
        int full = incl + sbuf[wid] + carry;   // inclusive within whole array
        if (i < n) {
            off[i + 1] = full;
            cur[i]     = full - v;             // exclusive (start position)
        }
        carry += sbuf[16];
        __syncthreads();                       // protect sbuf for next chunk
    }
}

__global__ __launch_bounds__(1024) void scan2_k(const int* cnt_h, int* off_h, int* cur_h, int nh,
                                                const int* cnt_v, int* off_v, int* cur_v, int nv) {
    __shared__ int sbuf[17];
    scan_one(cnt_h, off_h, cur_h, nh, sbuf);
    __syncthreads();
    scan_one(cnt_v, off_v, cur_v, nv, sbuf);
}

// ---------------- CSR fill (counting-sort scatter of 4B indices) -----------------
__global__ void fill_k(const int* __restrict__ nodes, const int* __restrict__ hedges,
                       int* __restrict__ cur_v, int* __restrict__ cur_h,
                       int* __restrict__ adj_v, int* __restrict__ adj_h, int E) {
    int e = blockIdx.x * 256 + threadIdx.x;
    if (e < E) {
        int v = nodes[e], h = hedges[e];
        int p = atomicAdd(&cur_h[h], 1);
        adj_h[p] = v;                 // hyperedge -> member node list
        int q = atomicAdd(&cur_v[v], 1);
        adj_v[q] = h;                 // node -> incident hyperedge list
    }
}

// ---------------- pass A: m[h] = B_inv[h] * sum_{v in h} x[v] --------------------
__global__ __launch_bounds__(256) void agg_a_k(const float* __restrict__ x,
                                               const int* __restrict__ adj,
                                               const int* __restrict__ off,
                                               float* __restrict__ m) {
    int h = blockIdx.x * 4 + (threadIdx.x >> 6);
    int l = threadIdx.x & 63;
    int s = off[h], e = off[h + 1];
    float ax = 0.f, ay = 0.f;
#pragma unroll 4
    for (int i = s; i < e; ++i) {
        int n = adj[i];
        float2 v = *(const float2*)(x + (size_t)n * 128 + 2 * l);
        ax += v.x; ay += v.y;
    }
    float inv = (e > s) ? 1.0f / (float)(e - s) : 0.0f;
    ((float2*)m)[(size_t)h * 64 + l] = make_float2(ax * inv, ay * inv);
}

// ---------------- pass B: out[v] = softmax(D_inv[v]*sum m[h] + b) ----------------
__global__ __launch_bounds__(256) void agg_b_k(const float* __restrict__ m,
                                               const int* __restrict__ adj,
                                               const int* __restrict__ off,
                                               const float* __restrict__ bias,
                                               float* __restrict__ out) {
    int v = blockIdx.x * 4 + (threadIdx.x >> 6);
    int l = threadIdx.x & 63;
    int s = off[v], e = off[v + 1];
    float ax = 0.f, ay = 0.f;
#pragma unroll 4
    for (int i = s; i < e; ++i) {
        int h = adj[i];
        float2 t = *(const float2*)(m + (size_t)h * 128 + 2 * l);
        ax += t.x; ay += t.y;
    }
    float inv = (e > s) ? 1.0f / (float)(e - s) : 0.0f;
    float2 bb = ((const float2*)bias)[l];
    float v0 = ax * inv + bb.x;
    float v1 = ay * inv + bb.y;

    // row softmax over 128 cols (2 per lane, 64 lanes)
    float mx = fmaxf(v0, v1);
#pragma unroll
    for (int s2 = 32; s2 >= 1; s2 >>= 1) mx = fmaxf(mx, __shfl_xor(mx, s2, 64));
    float e0 = __expf(v0 - mx), e1 = __expf(v1 - mx);
    float sm = e0 + e1;
#pragma unroll
    for (int s2 = 32; s2 >= 1; s2 >>= 1) sm += __shfl_xor(sm, s2, 64);
    float r = 1.0f / sm;
    ((float2*)out)[(size_t)v * 64 + l] = make_float2(e0 * r, e1 * r);
}

// ---------------- launcher -------------------------------------------------------
extern "C" void kernel_launch(void* const* d_in, const int* in_sizes, int n_in,
                              void* d_out, int out_size, void* d_ws, size_t ws_size,
                              hipStream_t stream) {
    const float* X  = (const float*)d_in[0];
    const int*   ei = (const int*)d_in[1];
    const float* W  = (const float*)d_in[2];
    const float* b  = (const float*)d_in[3];
    float* out = (float*)d_out;

    int E = in_sizes[1] / 2;
    const int* nodes  = ei;
    const int* hedges = ei + E;

    // workspace layout
    float* x     = (float*)d_ws;                     // NN*F floats
    float* m     = x + (size_t)NN * F;               // NM*F floats
    int*   adj_h = (int*)(m + (size_t)NM * F);       // E
    int*   adj_v = adj_h + E;                        // E
    int*   cnt_h = adj_v + E;                        // NM
    int*   cnt_v = cnt_h + NM;                       // NN
    int*   off_h = cnt_v + NN;                       // NM+1
    int*   cur_h = off_h + NM + 1;                   // NM
    int*   off_v = cur_h + NM;                       // NN+1
    int*   cur_v = off_v + NN + 1;                   // NN

    hipMemsetAsync(cnt_h, 0, sizeof(int) * (size_t)(NM + NN), stream);

    gemm_k<<<NN / 16, 256, 0, stream>>>(X, W, x);
    count_k<<<(E + 255) / 256, 256, 0, stream>>>(nodes, hedges, cnt_v, cnt_h, E);
    scan2_k<<<1, 1024, 0, stream>>>(cnt_h, off_h, cur_h, NM, cnt_v, off_v, cur_v, NN);
    fill_k<<<(E + 255) / 256, 256, 0, stream>>>(nodes, hedges, cur_v, cur_h, adj_v, adj_h, E);
    agg_a_k<<<NM / 4, 256, 0, stream>>>(x, adj_h, off_h, m);
    agg_b_k<<<NN / 4, 256, 0, stream>>>(m, adj_v, off_v, b, out);
}